// Round 12
// baseline (123.848 us; speedup 1.0000x reference)
//
#include <hip/hip_runtime.h>
#include <stdint.h>

// FSUMGUCell: hy = (1-fg)*ng + fg*hx
//   fg = ( [hx|x]@w_f^T + b_f + 1 ) * 0.5
//   ng =   [fg*hx|x]@w_n^T + b_n
// B=H=I=2048, K=H+I=4096. bf16 MFMA path.
//
// Round 12: "flatmm-lite". r11 was ~95% LDS-port-bound (96KB ds_read +
// 48KB ds_write per dual-block step ~= the whole 1760 cyc budget). B moves
// out of LDS: prep packs W into fragment-major Wp[colblk][kblk][lane][8],
// so a wave's B-fragment = one coalesced 1KB global_load_dwordx4 from L2
// (reused 16x across tm -> L2/L3-resident). LDS stages A only (32 KB dbuf).
// DS demand halves -> new floor ~27us/GEMM. Core otherwise = r11 verified:
// 128x64 tiles, grid 512 (2 blocks/CU), BK=64, counted vmcnt(8), fused epi.

#define Hdim 2048
#define Idim 2048
#define Bdim 2048
#define Ktot 4096
#define KHALF 2048
#define NSTEP 64            // Ktot / 64
#define NSTEP2 32           // K-half boundary in BK units

typedef __bf16 bf16;
typedef __bf16 bf16x8 __attribute__((ext_vector_type(8)));
typedef float  f32x4  __attribute__((ext_vector_type(4)));

__device__ __forceinline__ void gload_lds16(const bf16* g, bf16* l) {
  __builtin_amdgcn_global_load_lds(
      (const __attribute__((address_space(1))) unsigned int*)g,
      (__attribute__((address_space(3))) unsigned int*)l,
      16, 0, 0);
}

__device__ __forceinline__ void cvt8(const float* __restrict__ src, bf16* __restrict__ dst) {
  const float4* s = (const float4*)src;
  float4 a = s[0], b = s[1];
  bf16x8 o;
  o[0]=(bf16)a.x; o[1]=(bf16)a.y; o[2]=(bf16)a.z; o[3]=(bf16)a.w;
  o[4]=(bf16)b.x; o[5]=(bf16)b.y; o[6]=(bf16)b.z; o[7]=(bf16)b.w;
  *(bf16x8*)dst = o;
}

// ---- fused prep: pack Wf,Wn fragment-major | A1 = [hx|x] bf16 ----
// Wp elem index = ((c*128 + kb)*64 + l)*8 + j  holds  W[c*16 + (l&15)][kb*32 + (l>>4)*8 + j]
// -> a wave's fragment load (lane l, 16B) is contiguous 1KB.
__global__ void prep_kernel(const float* __restrict__ w_f, const float* __restrict__ w_n,
                            const float* __restrict__ hx, const float* __restrict__ x,
                            bf16* __restrict__ Wfp, bf16* __restrict__ Wnp,
                            bf16* __restrict__ A1) {
  const int n8 = Hdim * Ktot / 8;           // 1,048,576 per segment
  int stride = gridDim.x * blockDim.x;
  for (int i = blockIdx.x * blockDim.x + threadIdx.x; i < 3 * n8; i += stride) {
    if (i < 2 * n8) {
      int j = (i < n8) ? i : i - n8;
      const float* wsrc = (i < n8) ? w_f : w_n;
      bf16* wdst = (i < n8) ? Wfp : Wnp;
      int c  = j >> 13;          // /8192 : col-block of 16
      int rem = j & 8191;
      int kb = rem >> 6;         // /64   : k-block of 32
      int l  = rem & 63;         // lane
      const float* src = wsrc + ((size_t)c * 16 + (l & 15)) * Ktot + kb * 32 + (l >> 4) * 8;
      cvt8(src, wdst + (size_t)j * 8);
    } else {
      int j = i - 2 * n8;
      int e = j * 8;
      int b = e >> 12;           // / 4096
      int k = e & (Ktot - 1);
      const float* src = (k < Hdim) ? (hx + (size_t)b * Hdim + k)
                                    : (x  + (size_t)b * Idim + (k - Hdim));
      cvt8(src, A1 + (size_t)e);
    }
  }
}

// ---- 128x64 x K=4096 GEMM, 4 waves, A-in-LDS + B-in-regs, fused epilogue ----
// grid 512 = 16 tm x 32 tn. C[row][col] = sum_k A[row][k] * W[col][k].
// A K-halves: (Ab0,sA0) k<2048, (Ab1,sA1) k>=2048. LDS: A only, [buf][128*64]
// bf16 = 32 KB; 16B-chunk XOR swizzle (store c^(row&7) via inverse-swizzled
// global source; read with same XOR). B: packed Wp fragments, double-buffered
// in registers, loaded as 1KB coalesced dwordx4.
template<int EPI>
__global__ __launch_bounds__(256, 2)
void gemm_kernel(const bf16* __restrict__ Ab0, int sA0,
                 const bf16* __restrict__ Ab1, int sA1,
                 const bf16* __restrict__ Wp,
                 const float* __restrict__ bias,
                 const float* __restrict__ hx,   // EPI0 only
                 bf16* __restrict__ OMF,         // EPI0: write (1-fg) ; EPI1: read
                 bf16* __restrict__ A2L,         // EPI0: write bf16(fg*hx) ; EPI1: read
                 float* __restrict__ OUT)        // EPI1: write hy
{
  __shared__ bf16 lds[2][8192];   // A only = 32 KB

  int bid  = blockIdx.x;
  int sbid = (bid & 7) * 64 + (bid >> 3);   // XCD swizzle (512%8==0, bijective)
  int tm = sbid >> 5, tn = sbid & 31;       // 16 x 32 tiles of 128x64

  int tid = threadIdx.x;
  int w = tid >> 6, lane = tid & 63;
  int wrow = (w >> 1) * 64;     // 2x2 wave grid over 128x64: 64x32 per wave
  int wcol = (w & 1) * 32;
  int fr = lane & 15, fq = lane >> 4;
  int swz = fr & 7;

  // A staging: 1024 16B chunks/step, 256 thr -> 4 loads/thread.
  int srow = tid >> 3;                  // 0..31
  int csrc = (tid & 7) ^ (srow & 7);
  const bf16* pA0 = Ab0 + (size_t)(tm * 128 + srow) * sA0 + csrc * 8;
  const bf16* pA1 = Ab1 + (size_t)(tm * 128 + srow) * sA1 + csrc * 8;
  int lb = w * 512;                     // wave-uniform LDS base; gload adds lane*16B

  // B fragments: cb(n) = tn*4 + (wcol>>4) + n; elem = cb*65536 + kb*512 + lane*8
  const bf16* pW = Wp + ((size_t)(tn * 4 + (wcol >> 4))) * 65536 + lane * 8;

#define STAGE_A(buf, t_) do {                                                  \
    const bf16* pa_ = ((t_) < NSTEP2) ? pA0 : pA1;                             \
    size_t sa_ = ((t_) < NSTEP2) ? (size_t)sA0 : (size_t)sA1;                  \
    size_t ko_ = ((t_) < NSTEP2) ? (size_t)(t_) * 64 : (size_t)((t_) - NSTEP2) * 64; \
    _Pragma("unroll")                                                          \
    for (int jj = 0; jj < 4; ++jj)                                             \
      gload_lds16(pa_ + (size_t)jj * 32 * sa_ + ko_, &lds[buf][jj * 2048 + lb]); \
  } while (0)

  // bv order: [kk*2 + n]: kk -> kb = t*2+kk (+512/elem-kb), n -> +65536
#define BLOAD(dst, t_) do {                                                    \
    size_t o_ = (size_t)(t_) * 1024;                                           \
    dst[0] = *(const bf16x8*)(pW + o_);                                        \
    dst[1] = *(const bf16x8*)(pW + o_ + 65536);                                \
    dst[2] = *(const bf16x8*)(pW + o_ + 512);                                  \
    dst[3] = *(const bf16x8*)(pW + o_ + 512 + 65536);                          \
  } while (0)

  f32x4 acc[4][2] = {};

#define COMPUTE(buf, B_) do {                                                  \
    _Pragma("unroll")                                                          \
    for (int kk = 0; kk < 2; ++kk) {                                           \
      bf16x8 af[4];                                                            \
      int ch = ((kk * 4 + fq) ^ swz) * 8;                                      \
      _Pragma("unroll")                                                        \
      for (int m = 0; m < 4; ++m)                                              \
        af[m] = *(const bf16x8*)&lds[buf][(wrow + m * 16 + fr) * 64 + ch];     \
      __builtin_amdgcn_s_setprio(1);                                           \
      _Pragma("unroll")                                                        \
      for (int m = 0; m < 4; ++m)                                              \
        _Pragma("unroll")                                                      \
        for (int n = 0; n < 2; ++n)                                            \
          acc[m][n] = __builtin_amdgcn_mfma_f32_16x16x32_bf16(af[m], B_[kk * 2 + n], acc[m][n], 0, 0, 0); \
      __builtin_amdgcn_s_setprio(0);                                           \
    }                                                                          \
  } while (0)

#define ITER(t_, buf, bcur, bnext) do {                                        \
    if ((t_) + 1 < NSTEP) {                                                    \
      STAGE_A((buf) ^ 1, (t_) + 1);                                            \
      BLOAD(bnext, (t_) + 1);                                                  \
      asm volatile("s_waitcnt vmcnt(8)" ::: "memory");  /* A(t),B(t) landed */ \
    } else {                                                                   \
      asm volatile("s_waitcnt vmcnt(0)" ::: "memory");                         \
    }                                                                          \
    __builtin_amdgcn_s_barrier();                                              \
    COMPUTE(buf, bcur);                                                        \
    __builtin_amdgcn_s_barrier();                                              \
  } while (0)

  bf16x8 bA[4], bB[4];
  BLOAD(bA, 0);
  STAGE_A(0, 0);
  #pragma unroll 1
  for (int th = 0; th < NSTEP / 2; ++th) {   // static breg/buf parity (rule #20)
    ITER(2 * th,     0, bA, bB);
    ITER(2 * th + 1, 1, bB, bA);
  }
#undef ITER
#undef COMPUTE
#undef BLOAD
#undef STAGE_A

  // ---- fused epilogue. C/D layout: col = lane&15, row = (lane>>4)*4+i [m89]
  int row0 = tm * 128 + wrow + fq * 4;
  int col0 = tn * 64 + wcol + fr;
  #pragma unroll
  for (int n = 0; n < 2; ++n) {
    int gcol = col0 + n * 16;
    float bv2 = bias[gcol];
    #pragma unroll
    for (int m = 0; m < 4; ++m) {
      #pragma unroll
      for (int i = 0; i < 4; ++i) {
        int grow = row0 + m * 16 + i;
        size_t idx = (size_t)grow * Hdim + gcol;
        float v = acc[m][n][i] + bv2;
        if (EPI == 0) {
          float fg = (v + 1.0f) * 0.5f;
          OMF[idx] = (bf16)(1.0f - fg);
          A2L[idx] = (bf16)(fg * hx[idx]);
        } else {
          OUT[idx] = (float)OMF[idx] * v + (float)A2L[idx];  // (1-fg)*ng + fg*hx
        }
      }
    }
  }
}

extern "C" void kernel_launch(void* const* d_in, const int* in_sizes, int n_in,
                              void* d_out, int out_size, void* d_ws, size_t ws_size,
                              hipStream_t stream) {
  const float* x   = (const float*)d_in[0];
  const float* hx  = (const float*)d_in[1];
  const float* w_f = (const float*)d_in[2];
  const float* b_f = (const float*)d_in[3];
  const float* w_n = (const float*)d_in[4];
  const float* b_n = (const float*)d_in[5];
  float* out = (float*)d_out;

  bf16* A1  = (bf16*)d_ws;                         // [2048][4096] = 16 MB
  bf16* A2L = A1  + (size_t)Bdim * Ktot;           // [2048][2048] =  8 MB
  bf16* Wfp = A2L + (size_t)Bdim * KHALF;          // packed, 16 MB
  bf16* Wnp = Wfp + (size_t)Hdim * Ktot;           // packed, 16 MB
  bf16* OMF = Wnp + (size_t)Hdim * Ktot;           // [2048][2048] =  8 MB
  // ws total: 64 MB

  prep_kernel<<<2048, 256, 0, stream>>>(w_f, w_n, hx, x, Wfp, Wnp, A1);

  // GEMM1: A = A1 (both K-halves); fused epilogue -> OMF + A2L.
  gemm_kernel<0><<<512, 256, 0, stream>>>(A1, Ktot, A1 + KHALF, Ktot, Wfp, b_f,
                                          hx, OMF, A2L, nullptr);
  // GEMM2: A = [A2L | A1 right half (x)]; fused epilogue -> hy.
  gemm_kernel<1><<<512, 256, 0, stream>>>(A2L, KHALF, A1 + Hdim, Ktot, Wnp, b_n,
                                          nullptr, OMF, A2L, out);
}